// Round 1
// baseline (205.196 us; speedup 1.0000x reference)
//
#include <hip/hip_runtime.h>

// Bahdanau additive attention, f32 baseline.
// Shapes: B=8, TQ=128, TK=512, NIN=512 (q/k feature dim), H=128, NV=512.
// out = [context (B*TQ*NV), attn (B*TQ*TK)] f32.

#define B_    8
#define TQ_   128
#define TK_   512
#define NIN_  512
#define H_    128
#define NV_   512

__device__ __forceinline__ float fexp2(float x) {
#if __has_builtin(__builtin_amdgcn_exp2f)
    return __builtin_amdgcn_exp2f(x);
#else
    return exp2f(x);
#endif
}
__device__ __forceinline__ float frcp(float x) {
#if __has_builtin(__builtin_amdgcn_rcpf)
    return __builtin_amdgcn_rcpf(x);
#else
    return 1.0f / x;
#endif
}

// tanh(x) = 1 - 2/(exp2(2*log2e*x)+1); exact at +-inf, ~1e-6 abs error.
__device__ __forceinline__ float fast_tanh(float x) {
    float e = fexp2(x * 2.8853900817779268f);   // 2*log2(e)
    return 1.0f - 2.0f * frcp(e + 1.0f);
}

// ---------------------------------------------------------------- init ----
// qp <- bq broadcast, kp <- bk broadcast (atomicAdd accumulates on top),
// context region of out <- 0 (atomicAdd accumulates).
__global__ __launch_bounds__(256) void init_kernel(
        float* __restrict__ qp, float* __restrict__ kp,
        const float* __restrict__ bq, const float* __restrict__ bk,
        float* __restrict__ out_ctx) {
    int idx = blockIdx.x * 256 + threadIdx.x;
    int stride = gridDim.x * 256;
    for (int i = idx; i < B_ * TQ_ * H_; i += stride) qp[i] = bq[i & (H_ - 1)];
    for (int i = idx; i < B_ * TK_ * H_; i += stride) kp[i] = bk[i & (H_ - 1)];
    for (int i = idx; i < B_ * TQ_ * NV_; i += stride) out_ctx[i] = 0.0f;
}

// ---------------------------------------------------------------- proj ----
// outp[row, h] += sum_{k in chunk} in[row, k] * W[h, k]   (NT gemm, split-K)
// block: 256 thr, tile 64 rows x 128 h, K-chunk 128 (4 steps of BK=32).
__global__ __launch_bounds__(256) void proj_kernel(
        const float* __restrict__ in, const float* __restrict__ W,
        float* __restrict__ outp) {
    __shared__ float at[32][64];    // [kk][row] transposed
    __shared__ float wt[32][128];   // [kk][h]  transposed
    const int tid  = threadIdx.x;
    const int row0 = blockIdx.x * 64;
    const int kc   = blockIdx.y * 128;
    const int rg4  = (tid >> 4) * 4;   // 4 rows / thread
    const int hg8  = (tid & 15) * 8;   // 8 h / thread
    float acc[4][8];
#pragma unroll
    for (int i = 0; i < 4; ++i)
#pragma unroll
        for (int j = 0; j < 8; ++j) acc[i][j] = 0.0f;

    for (int t = 0; t < 4; ++t) {
        const int kbase = kc + t * 32;
        __syncthreads();
#pragma unroll
        for (int p = 0; p < 2; ++p) {           // stage A (64x32) transposed
            int idx = tid + p * 256;
            int r = idx >> 3, kq = (idx & 7) * 4;
            float4 v = *(const float4*)&in[(row0 + r) * NIN_ + kbase + kq];
            at[kq + 0][r] = v.x; at[kq + 1][r] = v.y;
            at[kq + 2][r] = v.z; at[kq + 3][r] = v.w;
        }
#pragma unroll
        for (int p = 0; p < 4; ++p) {           // stage W (128x32) transposed
            int idx = tid + p * 256;
            int h = idx >> 3, kq = (idx & 7) * 4;
            float4 v = *(const float4*)&W[h * NIN_ + kbase + kq];
            wt[kq + 0][h] = v.x; wt[kq + 1][h] = v.y;
            wt[kq + 2][h] = v.z; wt[kq + 3][h] = v.w;
        }
        __syncthreads();
#pragma unroll 8
        for (int kk = 0; kk < 32; ++kk) {
            float4 a  = *(const float4*)&at[kk][rg4];
            float4 b0 = *(const float4*)&wt[kk][hg8];
            float4 b1 = *(const float4*)&wt[kk][hg8 + 4];
            float av[4] = {a.x, a.y, a.z, a.w};
            float bv[8] = {b0.x, b0.y, b0.z, b0.w, b1.x, b1.y, b1.z, b1.w};
#pragma unroll
            for (int i = 0; i < 4; ++i)
#pragma unroll
                for (int j = 0; j < 8; ++j)
                    acc[i][j] = fmaf(av[i], bv[j], acc[i][j]);
        }
    }
#pragma unroll
    for (int i = 0; i < 4; ++i)
#pragma unroll
        for (int j = 0; j < 8; ++j)
            atomicAdd(&outp[(row0 + rg4 + i) * H_ + hg8 + j], acc[i][j]);
}

// -------------------------------------------------------------- scores ----
// Per block: batch b, 4 q rows. scores -> softmax -> attn (written to out).
__global__ __launch_bounds__(256) void scores_kernel(
        const float* __restrict__ qp, const float* __restrict__ kp,
        const float* __restrict__ Wo, const float* __restrict__ bo,
        float* __restrict__ out_attn) {
    __shared__ float qs[4][H_];
    __shared__ float wos[H_];
    __shared__ float sc[4][TK_];
    const int tid = threadIdx.x;
    const int b   = blockIdx.y;
    const int q0  = blockIdx.x * 4;

#pragma unroll
    for (int p = 0; p < 2; ++p) {
        int idx = tid + p * 256;                 // 0..511
        qs[idx >> 7][idx & 127] =
            qp[(b * TQ_ + q0 + (idx >> 7)) * H_ + (idx & 127)];
    }
    if (tid < H_) wos[tid] = Wo[tid];
    __syncthreads();
    const float bo0 = bo[0];

#pragma unroll
    for (int half = 0; half < 2; ++half) {
        const int k = tid + half * 256;
        const float4* kp4 = (const float4*)&kp[(b * TK_ + k) * H_];
        float acc[4] = {0.f, 0.f, 0.f, 0.f};
#pragma unroll 4
        for (int hb = 0; hb < 32; ++hb) {
            float4 kv = kp4[hb];
            float4 wv = *(const float4*)&wos[hb * 4];
#pragma unroll
            for (int qi = 0; qi < 4; ++qi) {
                float4 qv = *(const float4*)&qs[qi][hb * 4];
                float t0 = fast_tanh(qv.x + kv.x);
                float t1 = fast_tanh(qv.y + kv.y);
                float t2 = fast_tanh(qv.z + kv.z);
                float t3 = fast_tanh(qv.w + kv.w);
                acc[qi] = fmaf(wv.x, t0, acc[qi]);
                acc[qi] = fmaf(wv.y, t1, acc[qi]);
                acc[qi] = fmaf(wv.z, t2, acc[qi]);
                acc[qi] = fmaf(wv.w, t3, acc[qi]);
            }
        }
        sc[0][k] = acc[0] + bo0;
        sc[1][k] = acc[1] + bo0;
        sc[2][k] = acc[2] + bo0;
        sc[3][k] = acc[3] + bo0;
    }
    __syncthreads();

    // softmax: one wave per q row, 8 scores per lane
    const int w = tid >> 6, lane = tid & 63;
    float4 sA = *(const float4*)&sc[w][lane * 8];
    float4 sB = *(const float4*)&sc[w][lane * 8 + 4];
    float m = fmaxf(fmaxf(fmaxf(sA.x, sA.y), fmaxf(sA.z, sA.w)),
                    fmaxf(fmaxf(sB.x, sB.y), fmaxf(sB.z, sB.w)));
#pragma unroll
    for (int mask = 1; mask < 64; mask <<= 1) m = fmaxf(m, __shfl_xor(m, mask));
    const float L2E = 1.4426950408889634f;
    float4 eA, eB;
    eA.x = fexp2((sA.x - m) * L2E); eA.y = fexp2((sA.y - m) * L2E);
    eA.z = fexp2((sA.z - m) * L2E); eA.w = fexp2((sA.w - m) * L2E);
    eB.x = fexp2((sB.x - m) * L2E); eB.y = fexp2((sB.y - m) * L2E);
    eB.z = fexp2((sB.z - m) * L2E); eB.w = fexp2((sB.w - m) * L2E);
    float s = eA.x + eA.y + eA.z + eA.w + eB.x + eB.y + eB.z + eB.w;
#pragma unroll
    for (int mask = 1; mask < 64; mask <<= 1) s += __shfl_xor(s, mask);
    float inv = frcp(s);
    eA.x *= inv; eA.y *= inv; eA.z *= inv; eA.w *= inv;
    eB.x *= inv; eB.y *= inv; eB.z *= inv; eB.w *= inv;
    float4* op = (float4*)&out_attn[(b * TQ_ + q0 + w) * TK_ + lane * 8];
    op[0] = eA; op[1] = eB;
}

// ------------------------------------------------------------- context ----
// outc[b,q,v] += sum_{k in chunk} attn[b,q,k] * values[b,k,v]  (NN, split-K)
// block: 256 thr, tile 64 q x 128 v, K-chunk 128.
__global__ __launch_bounds__(256) void context_kernel(
        const float* __restrict__ attn, const float* __restrict__ values,
        float* __restrict__ outc) {
    __shared__ float at[32][64];    // [kk][q] transposed
    __shared__ float vt[32][128];   // [kk][v] natural
    const int tid = threadIdx.x;
    const int b   = blockIdx.y;
    const int q0  = (blockIdx.x & 1) * 64;
    const int v0  = (blockIdx.x >> 1) * 128;
    const int kc  = blockIdx.z * 128;
    const int rg4 = (tid >> 4) * 4;
    const int vg8 = (tid & 15) * 8;
    float acc[4][8];
#pragma unroll
    for (int i = 0; i < 4; ++i)
#pragma unroll
        for (int j = 0; j < 8; ++j) acc[i][j] = 0.0f;

    for (int t = 0; t < 4; ++t) {
        const int kbase = kc + t * 32;
        __syncthreads();
#pragma unroll
        for (int p = 0; p < 2; ++p) {           // stage attn (64x32) transposed
            int idx = tid + p * 256;
            int r = idx >> 3, kq = (idx & 7) * 4;
            float4 v = *(const float4*)&attn[(b * TQ_ + q0 + r) * TK_ + kbase + kq];
            at[kq + 0][r] = v.x; at[kq + 1][r] = v.y;
            at[kq + 2][r] = v.z; at[kq + 3][r] = v.w;
        }
#pragma unroll
        for (int p = 0; p < 4; ++p) {           // stage values (32x128)
            int idx = tid + p * 256;
            int kk = idx >> 5, vq = (idx & 31) * 4;
            float4 v = *(const float4*)&values[(b * TK_ + kbase + kk) * NV_ + v0 + vq];
            *(float4*)&vt[kk][vq] = v;
        }
        __syncthreads();
#pragma unroll 8
        for (int kk = 0; kk < 32; ++kk) {
            float4 a  = *(const float4*)&at[kk][rg4];
            float4 b0 = *(const float4*)&vt[kk][vg8];
            float4 b1 = *(const float4*)&vt[kk][vg8 + 4];
            float av[4] = {a.x, a.y, a.z, a.w};
            float bv[8] = {b0.x, b0.y, b0.z, b0.w, b1.x, b1.y, b1.z, b1.w};
#pragma unroll
            for (int i = 0; i < 4; ++i)
#pragma unroll
                for (int j = 0; j < 8; ++j)
                    acc[i][j] = fmaf(av[i], bv[j], acc[i][j]);
        }
    }
#pragma unroll
    for (int i = 0; i < 4; ++i)
#pragma unroll
        for (int j = 0; j < 8; ++j)
            atomicAdd(&outc[(b * TQ_ + q0 + rg4 + i) * NV_ + v0 + vg8 + j],
                      acc[i][j]);
}

// -------------------------------------------------------------- launch ----
extern "C" void kernel_launch(void* const* d_in, const int* in_sizes, int n_in,
                              void* d_out, int out_size, void* d_ws, size_t ws_size,
                              hipStream_t stream) {
    const float* query  = (const float*)d_in[0];
    const float* keys   = (const float*)d_in[1];
    const float* values = (const float*)d_in[2];
    const float* Wq     = (const float*)d_in[3];
    const float* bq     = (const float*)d_in[4];
    const float* Wk     = (const float*)d_in[5];
    const float* bk     = (const float*)d_in[6];
    const float* Wo     = (const float*)d_in[7];
    const float* bo     = (const float*)d_in[8];

    float* out_ctx  = (float*)d_out;                 // B*TQ*NV
    float* out_attn = out_ctx + B_ * TQ_ * NV_;      // B*TQ*TK
    float* qp = (float*)d_ws;                        // B*TQ*H
    float* kp = qp + B_ * TQ_ * H_;                  // B*TK*H

    init_kernel<<<1024, 256, 0, stream>>>(qp, kp, bq, bk, out_ctx);
    proj_kernel<<<dim3(B_ * TQ_ / 64, 4), 256, 0, stream>>>(query, Wq, qp);
    proj_kernel<<<dim3(B_ * TK_ / 64, 4), 256, 0, stream>>>(keys, Wk, kp);
    scores_kernel<<<dim3(TQ_ / 4, B_), 256, 0, stream>>>(qp, kp, Wo, bo, out_attn);
    context_kernel<<<dim3(8, B_, 4), 256, 0, stream>>>(out_attn, values, out_ctx);
}

// Round 2
// 88.274 us; speedup vs baseline: 2.3245x; 2.3245x over previous
//
#include <hip/hip_runtime.h>

// Bahdanau additive attention, f32. Shapes: B=8, TQ=128, TK=512,
// NIN=512 (q/k feature dim), H=128, NV=512.
// out = [context (B*TQ*NV), attn (B*TQ*TK)] f32.

#define B_    8
#define TQ_   128
#define TK_   512
#define NIN_  512
#define H_    128
#define NV_   512

#define C2_   2.8853900817779268f   // 2*log2(e): exp2(C2*x) = e^(2x)
#define L2E_  1.4426950408889634f

__device__ __forceinline__ float fexp2(float x) {
    return __builtin_amdgcn_exp2f(x);
}
__device__ __forceinline__ float frcp(float x) {
    return __builtin_amdgcn_rcpf(x);
}

// ---------------------------------------------------------------- proj ----
// One block: 16 rows x 128 h, full K=512 (no split, no atomics).
// Blocks 0..63  -> query rows -> qp (with bq)
// Blocks 64..319-> key rows   -> kp (with bk)
__global__ __launch_bounds__(256, 2) void proj_kernel(
        const float* __restrict__ query, const float* __restrict__ keys,
        const float* __restrict__ Wq, const float* __restrict__ bq,
        const float* __restrict__ Wk, const float* __restrict__ bk,
        float* __restrict__ qp, float* __restrict__ kp) {
    __shared__ float at[32][18];    // [kk][row], pad 18 keeps writes 2-way + float2 aligned
    __shared__ float wt[32][132];   // [kk][h], pad 132

    const int tid  = threadIdx.x;
    const int row0 = blockIdx.x * 16;
    const float* in; const float* W; const float* bias; float* outp;
    if (row0 < B_ * TQ_) {
        in = query + row0 * NIN_; W = Wq; bias = bq; outp = qp + row0 * H_;
    } else {
        const int r = row0 - B_ * TQ_;
        in = keys + r * NIN_;     W = Wk; bias = bk; outp = kp + r * H_;
    }

    const int r2  = (tid >> 5) * 2;      // rows r2, r2+1 (0..15)
    const int hg4 = (tid & 31) * 4;      // 4 h columns
    float acc[2][4] = {{0.f,0.f,0.f,0.f},{0.f,0.f,0.f,0.f}};

    for (int kc = 0; kc < NIN_; kc += 32) {
        __syncthreads();
        if (tid < 128) {                      // stage A: 16 rows x 32 k, transposed
            int r = tid >> 3, kq = (tid & 7) * 4;
            float4 v = *(const float4*)&in[r * NIN_ + kc + kq];
            at[kq + 0][r] = v.x; at[kq + 1][r] = v.y;
            at[kq + 2][r] = v.z; at[kq + 3][r] = v.w;
        }
#pragma unroll
        for (int p = 0; p < 4; ++p) {         // stage W: 128 h x 32 k, transposed
            int idx = tid + p * 256;
            int h = idx >> 3, kq = (idx & 7) * 4;
            float4 v = *(const float4*)&W[h * NIN_ + kc + kq];
            wt[kq + 0][h] = v.x; wt[kq + 1][h] = v.y;
            wt[kq + 2][h] = v.z; wt[kq + 3][h] = v.w;
        }
        __syncthreads();
#pragma unroll 8
        for (int kk = 0; kk < 32; ++kk) {
            float2 a = *(const float2*)&at[kk][r2];
            float4 w = *(const float4*)&wt[kk][hg4];
            acc[0][0] = fmaf(a.x, w.x, acc[0][0]);
            acc[0][1] = fmaf(a.x, w.y, acc[0][1]);
            acc[0][2] = fmaf(a.x, w.z, acc[0][2]);
            acc[0][3] = fmaf(a.x, w.w, acc[0][3]);
            acc[1][0] = fmaf(a.y, w.x, acc[1][0]);
            acc[1][1] = fmaf(a.y, w.y, acc[1][1]);
            acc[1][2] = fmaf(a.y, w.z, acc[1][2]);
            acc[1][3] = fmaf(a.y, w.w, acc[1][3]);
        }
    }
    const float4 bv = *(const float4*)&bias[hg4];
    float4 o0 = {acc[0][0] + bv.x, acc[0][1] + bv.y, acc[0][2] + bv.z, acc[0][3] + bv.w};
    float4 o1 = {acc[1][0] + bv.x, acc[1][1] + bv.y, acc[1][2] + bv.z, acc[1][3] + bv.w};
    *(float4*)&outp[(r2 + 0) * H_ + hg4] = o0;
    *(float4*)&outp[(r2 + 1) * H_ + hg4] = o1;
}

// -------------------------------------------------------------- scores ----
// Per block: batch b, 4 q rows. scores -> softmax -> attn (written to out).
// score = bo + sum_h Wo_h*tanh(x_h) = bo + sumWo - 2*sum_h Wo_h/(e^(2x_h)+1)
__global__ __launch_bounds__(256, 2) void scores_kernel(
        const float* __restrict__ qp, const float* __restrict__ kp,
        const float* __restrict__ Wo, const float* __restrict__ bo,
        float* __restrict__ out_attn) {
    __shared__ float qs2[4][H_];    // q_proj * C2
    __shared__ float w2[H_];        // -2 * Wo
    __shared__ float sc[4][TK_];

    const int tid = threadIdx.x;
    const int b   = blockIdx.y;
    const int q0  = blockIdx.x * 4;
    const int lane = tid & 63;

#pragma unroll
    for (int p = 0; p < 2; ++p) {
        int idx = tid + p * 256;                 // 0..511
        qs2[idx >> 7][idx & 127] =
            qp[(b * TQ_ + q0 + (idx >> 7)) * H_ + (idx & 127)] * C2_;
    }
    if (tid < H_) w2[tid] = Wo[tid] * -2.0f;
    __syncthreads();

    // sumWo = -0.5 * sum(w2), per-wave shuffle reduce
    float sw = w2[lane] + w2[lane + 64];
#pragma unroll
    for (int m = 1; m < 64; m <<= 1) sw += __shfl_xor(sw, m);
    const float sbase = bo[0] - 0.5f * sw;

#pragma unroll
    for (int half = 0; half < 2; ++half) {
        const int k = tid + half * 256;
        const float4* kp4 = (const float4*)&kp[(b * TK_ + k) * H_];
        float acc[4] = {0.f, 0.f, 0.f, 0.f};
#pragma unroll 2
        for (int hb = 0; hb < 32; ++hb) {
            float4 kv = kp4[hb];
            kv.x *= C2_; kv.y *= C2_; kv.z *= C2_; kv.w *= C2_;
            float4 wv = *(const float4*)&w2[hb * 4];
#pragma unroll
            for (int qi = 0; qi < 4; ++qi) {
                float4 qv = *(const float4*)&qs2[qi][hb * 4];
                float r0 = frcp(fexp2(qv.x + kv.x) + 1.0f);
                float r1 = frcp(fexp2(qv.y + kv.y) + 1.0f);
                float r2 = frcp(fexp2(qv.z + kv.z) + 1.0f);
                float r3 = frcp(fexp2(qv.w + kv.w) + 1.0f);
                acc[qi] = fmaf(wv.x, r0, acc[qi]);
                acc[qi] = fmaf(wv.y, r1, acc[qi]);
                acc[qi] = fmaf(wv.z, r2, acc[qi]);
                acc[qi] = fmaf(wv.w, r3, acc[qi]);
            }
        }
        sc[0][k] = acc[0] + sbase;
        sc[1][k] = acc[1] + sbase;
        sc[2][k] = acc[2] + sbase;
        sc[3][k] = acc[3] + sbase;
    }
    __syncthreads();

    // softmax: one wave per q row, 8 scores per lane
    const int w = tid >> 6;
    float4 sA = *(const float4*)&sc[w][lane * 8];
    float4 sB = *(const float4*)&sc[w][lane * 8 + 4];
    float m = fmaxf(fmaxf(fmaxf(sA.x, sA.y), fmaxf(sA.z, sA.w)),
                    fmaxf(fmaxf(sB.x, sB.y), fmaxf(sB.z, sB.w)));
#pragma unroll
    for (int mask = 1; mask < 64; mask <<= 1) m = fmaxf(m, __shfl_xor(m, mask));
    float4 eA, eB;
    eA.x = fexp2((sA.x - m) * L2E_); eA.y = fexp2((sA.y - m) * L2E_);
    eA.z = fexp2((sA.z - m) * L2E_); eA.w = fexp2((sA.w - m) * L2E_);
    eB.x = fexp2((sB.x - m) * L2E_); eB.y = fexp2((sB.y - m) * L2E_);
    eB.z = fexp2((sB.z - m) * L2E_); eB.w = fexp2((sB.w - m) * L2E_);
    float s = eA.x + eA.y + eA.z + eA.w + eB.x + eB.y + eB.z + eB.w;
#pragma unroll
    for (int mask = 1; mask < 64; mask <<= 1) s += __shfl_xor(s, mask);
    float inv = frcp(s);
    eA.x *= inv; eA.y *= inv; eA.z *= inv; eA.w *= inv;
    eB.x *= inv; eB.y *= inv; eB.z *= inv; eB.w *= inv;
    float4* op = (float4*)&out_attn[(b * TQ_ + q0 + w) * TK_ + lane * 8];
    op[0] = eA; op[1] = eB;
}

// ------------------------------------------------------------- context ----
// One block: 16 q x 128 v, full K=512, direct stores (no atomics).
// grid: x = 32 (8 q-tiles x 4 v-tiles), y = batch
__global__ __launch_bounds__(256, 2) void context_kernel(
        const float* __restrict__ attn, const float* __restrict__ values,
        float* __restrict__ outc) {
    __shared__ float at[32][18];    // [kk][q] transposed
    __shared__ float vt[32][132];   // [kk][v] natural

    const int tid = threadIdx.x;
    const int b   = blockIdx.y;
    const int q0  = (blockIdx.x >> 2) * 16;
    const int v0  = (blockIdx.x & 3) * 128;

    const int r2  = (tid >> 5) * 2;
    const int vg4 = (tid & 31) * 4;
    float acc[2][4] = {{0.f,0.f,0.f,0.f},{0.f,0.f,0.f,0.f}};

    for (int kc = 0; kc < TK_; kc += 32) {
        __syncthreads();
        if (tid < 128) {                      // stage attn: 16 q x 32 k, transposed
            int r = tid >> 3, kq = (tid & 7) * 4;
            float4 v = *(const float4*)&attn[(b * TQ_ + q0 + r) * TK_ + kc + kq];
            at[kq + 0][r] = v.x; at[kq + 1][r] = v.y;
            at[kq + 2][r] = v.z; at[kq + 3][r] = v.w;
        }
#pragma unroll
        for (int p = 0; p < 4; ++p) {         // stage values: 32 k x 128 v
            int idx = tid + p * 256;
            int kk = idx >> 5, vq = (idx & 31) * 4;
            float4 v = *(const float4*)&values[(b * TK_ + kc + kk) * NV_ + v0 + vq];
            *(float4*)&vt[kk][vq] = v;
        }
        __syncthreads();
#pragma unroll 8
        for (int kk = 0; kk < 32; ++kk) {
            float2 a = *(const float2*)&at[kk][r2];
            float4 v = *(const float4*)&vt[kk][vg4];
            acc[0][0] = fmaf(a.x, v.x, acc[0][0]);
            acc[0][1] = fmaf(a.x, v.y, acc[0][1]);
            acc[0][2] = fmaf(a.x, v.z, acc[0][2]);
            acc[0][3] = fmaf(a.x, v.w, acc[0][3]);
            acc[1][0] = fmaf(a.y, v.x, acc[1][0]);
            acc[1][1] = fmaf(a.y, v.y, acc[1][1]);
            acc[1][2] = fmaf(a.y, v.z, acc[1][2]);
            acc[1][3] = fmaf(a.y, v.w, acc[1][3]);
        }
    }
    float4 o0 = {acc[0][0], acc[0][1], acc[0][2], acc[0][3]};
    float4 o1 = {acc[1][0], acc[1][1], acc[1][2], acc[1][3]};
    *(float4*)&outc[(b * TQ_ + q0 + r2 + 0) * NV_ + v0 + vg4] = o0;
    *(float4*)&outc[(b * TQ_ + q0 + r2 + 1) * NV_ + v0 + vg4] = o1;
}

// -------------------------------------------------------------- launch ----
extern "C" void kernel_launch(void* const* d_in, const int* in_sizes, int n_in,
                              void* d_out, int out_size, void* d_ws, size_t ws_size,
                              hipStream_t stream) {
    const float* query  = (const float*)d_in[0];
    const float* keys   = (const float*)d_in[1];
    const float* values = (const float*)d_in[2];
    const float* Wq     = (const float*)d_in[3];
    const float* bq     = (const float*)d_in[4];
    const float* Wk     = (const float*)d_in[5];
    const float* bk     = (const float*)d_in[6];
    const float* Wo     = (const float*)d_in[7];
    const float* bo     = (const float*)d_in[8];

    float* out_ctx  = (float*)d_out;                 // B*TQ*NV
    float* out_attn = out_ctx + B_ * TQ_ * NV_;      // B*TQ*TK
    float* qp = (float*)d_ws;                        // B*TQ*H
    float* kp = qp + B_ * TQ_ * H_;                  // B*TK*H

    proj_kernel<<<(B_ * TQ_ + B_ * TK_) / 16, 256, 0, stream>>>(
        query, keys, Wq, bq, Wk, bk, qp, kp);
    scores_kernel<<<dim3(TQ_ / 4, B_), 256, 0, stream>>>(qp, kp, Wo, bo, out_attn);
    context_kernel<<<dim3(32, B_), 256, 0, stream>>>(out_attn, values, out_ctx);
}

// Round 3
// 71.020 us; speedup vs baseline: 2.8893x; 1.2429x over previous
//
#include <hip/hip_runtime.h>

// Bahdanau additive attention, f32. B=8, TQ=128, TK=512, NIN=512, H=128, NV=512.
// out = [context (B*TQ*NV), attn (B*TQ*TK)] f32.

#define B_    8
#define TQ_   128
#define TK_   512
#define NIN_  512
#define H_    128
#define NV_   512
#define NQR   (B_*TQ_)           // 1024 query rows
#define NROWS (NQR + B_*TK_)     // 5120 total projected rows

#define C2_   2.8853900817779268f   // 2*log2(e)
#define L2E_  1.4426950408889634f

__device__ __forceinline__ float fexp2(float x){ return __builtin_amdgcn_exp2f(x); }
__device__ __forceinline__ float frcp (float x){ return __builtin_amdgcn_rcpf(x); }

// ---------------------------------------------------------------- proj ----
// psum[s][row][h] = A[row, ks:ke) . W[h, ks:ke)   (+bias when nsplit==1)
// grid (NROWS/32, nsplit), 256 thr. Tile 32 rows x 128 h, K-chunk 32,
// register-prefetch pipeline (load chunk c+1 while computing chunk c).
__global__ __launch_bounds__(256, 4) void proj_kernel(
        const float* __restrict__ query, const float* __restrict__ keys,
        const float* __restrict__ Wq, const float* __restrict__ Wk,
        const float* __restrict__ bq, const float* __restrict__ bk,
        float* __restrict__ psum, int nsplit, int kper) {
    __shared__ float at[32][36];     // [kk][row]  (pad 36: aligned b128 reads)
    __shared__ float wt[32][132];    // [kk][h]    (pad 132: 2-way-free writes)
    const int tid = threadIdx.x;
    const int r0  = blockIdx.x * 32;
    const float* in; const float* W; const float* bias;
    if (r0 < NQR) { in = query + (size_t)r0 * NIN_;         W = Wq; bias = bq; }
    else          { in = keys  + (size_t)(r0 - NQR) * NIN_; W = Wk; bias = bk; }

    const int tx = tid & 31, ty = tid >> 5;
    const int h4 = tx * 4,   r4 = ty * 4;
    const int ar = tid >> 3, akq = (tid & 7) * 4;      // staging coords
    const int kb0 = blockIdx.y * kper;
    const int nc  = kper >> 5;

    const float* pA  = in + ar * NIN_ + kb0 + akq;
    const float* pW0 = W + (ar     ) * NIN_ + kb0 + akq;
    const float* pW1 = W + (ar + 32) * NIN_ + kb0 + akq;
    const float* pW2 = W + (ar + 64) * NIN_ + kb0 + akq;
    const float* pW3 = W + (ar + 96) * NIN_ + kb0 + akq;

    float4 af  = *(const float4*)pA;
    float4 wf0 = *(const float4*)pW0;
    float4 wf1 = *(const float4*)pW1;
    float4 wf2 = *(const float4*)pW2;
    float4 wf3 = *(const float4*)pW3;

    float acc[4][4];
#pragma unroll
    for (int i = 0; i < 4; ++i)
#pragma unroll
        for (int j = 0; j < 4; ++j) acc[i][j] = 0.0f;

    for (int c = 0; c < nc; ++c) {
        __syncthreads();
        at[akq+0][ar] = af.x;  at[akq+1][ar] = af.y;
        at[akq+2][ar] = af.z;  at[akq+3][ar] = af.w;
        wt[akq+0][ar   ] = wf0.x; wt[akq+1][ar   ] = wf0.y;
        wt[akq+2][ar   ] = wf0.z; wt[akq+3][ar   ] = wf0.w;
        wt[akq+0][ar+32] = wf1.x; wt[akq+1][ar+32] = wf1.y;
        wt[akq+2][ar+32] = wf1.z; wt[akq+3][ar+32] = wf1.w;
        wt[akq+0][ar+64] = wf2.x; wt[akq+1][ar+64] = wf2.y;
        wt[akq+2][ar+64] = wf2.z; wt[akq+3][ar+64] = wf2.w;
        wt[akq+0][ar+96] = wf3.x; wt[akq+1][ar+96] = wf3.y;
        wt[akq+2][ar+96] = wf3.z; wt[akq+3][ar+96] = wf3.w;
        __syncthreads();
        if (c + 1 < nc) {
            pA += 32; pW0 += 32; pW1 += 32; pW2 += 32; pW3 += 32;
            af  = *(const float4*)pA;
            wf0 = *(const float4*)pW0; wf1 = *(const float4*)pW1;
            wf2 = *(const float4*)pW2; wf3 = *(const float4*)pW3;
        }
#pragma unroll 8
        for (int kk = 0; kk < 32; ++kk) {
            float4 a = *(const float4*)&at[kk][r4];
            float4 w = *(const float4*)&wt[kk][h4];
            float av[4] = {a.x, a.y, a.z, a.w};
            float wv[4] = {w.x, w.y, w.z, w.w};
#pragma unroll
            for (int i = 0; i < 4; ++i)
#pragma unroll
                for (int j = 0; j < 4; ++j)
                    acc[i][j] = fmaf(av[i], wv[j], acc[i][j]);
        }
    }

    float4 b4 = {0.f, 0.f, 0.f, 0.f};
    if (nsplit == 1) b4 = *(const float4*)&bias[h4];
    float* op = psum + ((size_t)blockIdx.y * NROWS + r0) * H_;
#pragma unroll
    for (int i = 0; i < 4; ++i) {
        float4 o = {acc[i][0] + b4.x, acc[i][1] + b4.y,
                    acc[i][2] + b4.z, acc[i][3] + b4.w};
        *(float4*)&op[(r4 + i) * H_ + h4] = o;
    }
}

// -------------------------------------------------------------- reduce ----
// proj_out[row][h] = sum_s psum[s][row][h] + bias[h]
__global__ __launch_bounds__(256, 4) void reduce_kernel(
        const float* __restrict__ psum, const float* __restrict__ bq,
        const float* __restrict__ bk, float* __restrict__ pout, int nsplit) {
    const int i = blockIdx.x * 256 + threadIdx.x;    // float4 index
    const int row = i >> 5;
    const int h4  = (i & 31) * 4;
    const float* bias = (row < NQR) ? bq : bk;
    float4 s = *(const float4*)&bias[h4];
    for (int sp = 0; sp < nsplit; ++sp) {
        float4 p = *(const float4*)&psum[((size_t)sp * NROWS) * H_ + (size_t)i * 4];
        s.x += p.x; s.y += p.y; s.z += p.z; s.w += p.w;
    }
    *(float4*)&pout[(size_t)i * 4] = s;
}

// -------------------------------------------------------------- scores ----
// Per block: batch b, 4 q rows. scores -> softmax -> attn.
// score = bo + sumWo - 2*sum_h Wo_h/(e^(2x_h)+1)
__global__ __launch_bounds__(256, 2) void scores_kernel(
        const float* __restrict__ qp, const float* __restrict__ kp,
        const float* __restrict__ Wo, const float* __restrict__ bo,
        float* __restrict__ out_attn) {
    __shared__ float qs2[4][H_];    // q_proj * C2
    __shared__ float w2[H_];        // -2 * Wo
    __shared__ float sc[4][TK_];

    const int tid = threadIdx.x;
    const int b   = blockIdx.y;
    const int q0  = blockIdx.x * 4;
    const int lane = tid & 63;

#pragma unroll
    for (int p = 0; p < 2; ++p) {
        int idx = tid + p * 256;
        qs2[idx >> 7][idx & 127] =
            qp[(b * TQ_ + q0 + (idx >> 7)) * H_ + (idx & 127)] * C2_;
    }
    if (tid < H_) w2[tid] = Wo[tid] * -2.0f;
    __syncthreads();

    float sw = w2[lane] + w2[lane + 64];
#pragma unroll
    for (int m = 1; m < 64; m <<= 1) sw += __shfl_xor(sw, m);
    const float sbase = bo[0] - 0.5f * sw;

#pragma unroll
    for (int half = 0; half < 2; ++half) {
        const int k = tid + half * 256;
        const float4* kp4 = (const float4*)&kp[(b * TK_ + k) * H_];
        float acc[4] = {0.f, 0.f, 0.f, 0.f};
#pragma unroll 4
        for (int hb = 0; hb < 32; ++hb) {
            float4 kv = kp4[hb];
            kv.x *= C2_; kv.y *= C2_; kv.z *= C2_; kv.w *= C2_;
            float4 wv = *(const float4*)&w2[hb * 4];
#pragma unroll
            for (int qi = 0; qi < 4; ++qi) {
                float4 qv = *(const float4*)&qs2[qi][hb * 4];
                float r0 = frcp(fexp2(qv.x + kv.x) + 1.0f);
                float r1 = frcp(fexp2(qv.y + kv.y) + 1.0f);
                float r2 = frcp(fexp2(qv.z + kv.z) + 1.0f);
                float r3 = frcp(fexp2(qv.w + kv.w) + 1.0f);
                acc[qi] = fmaf(wv.x, r0, acc[qi]);
                acc[qi] = fmaf(wv.y, r1, acc[qi]);
                acc[qi] = fmaf(wv.z, r2, acc[qi]);
                acc[qi] = fmaf(wv.w, r3, acc[qi]);
            }
        }
        sc[0][k] = acc[0] + sbase;
        sc[1][k] = acc[1] + sbase;
        sc[2][k] = acc[2] + sbase;
        sc[3][k] = acc[3] + sbase;
    }
    __syncthreads();

    const int w = tid >> 6;
    float4 sA = *(const float4*)&sc[w][lane * 8];
    float4 sB = *(const float4*)&sc[w][lane * 8 + 4];
    float m = fmaxf(fmaxf(fmaxf(sA.x, sA.y), fmaxf(sA.z, sA.w)),
                    fmaxf(fmaxf(sB.x, sB.y), fmaxf(sB.z, sB.w)));
#pragma unroll
    for (int mask = 1; mask < 64; mask <<= 1) m = fmaxf(m, __shfl_xor(m, mask));
    float4 eA, eB;
    eA.x = fexp2((sA.x - m) * L2E_); eA.y = fexp2((sA.y - m) * L2E_);
    eA.z = fexp2((sA.z - m) * L2E_); eA.w = fexp2((sA.w - m) * L2E_);
    eB.x = fexp2((sB.x - m) * L2E_); eB.y = fexp2((sB.y - m) * L2E_);
    eB.z = fexp2((sB.z - m) * L2E_); eB.w = fexp2((sB.w - m) * L2E_);
    float s = eA.x + eA.y + eA.z + eA.w + eB.x + eB.y + eB.z + eB.w;
#pragma unroll
    for (int mask = 1; mask < 64; mask <<= 1) s += __shfl_xor(s, mask);
    float inv = frcp(s);
    eA.x *= inv; eA.y *= inv; eA.z *= inv; eA.w *= inv;
    eB.x *= inv; eB.y *= inv; eB.z *= inv; eB.w *= inv;
    float4* op = (float4*)&out_attn[(b * TQ_ + q0 + w) * TK_ + lane * 8];
    op[0] = eA; op[1] = eB;
}

// ------------------------------------------------------------- context ----
// One block: 16 q x 128 v, full K=512, reg-prefetch pipeline.
// grid (32 = 8 q-tiles x 4 v-tiles, B)
__global__ __launch_bounds__(256, 4) void context_kernel(
        const float* __restrict__ attn, const float* __restrict__ values,
        float* __restrict__ outc) {
    __shared__ float at[32][20];    // [kk][q]
    __shared__ float vt[32][132];   // [kk][v]

    const int tid = threadIdx.x;
    const int b   = blockIdx.y;
    const int q0  = (blockIdx.x >> 2) * 16;
    const int v0  = (blockIdx.x & 3) * 128;

    const int tx = tid & 31, ty = tid >> 5;
    const int v4 = tx * 4,   r2 = ty * 2;
    const int ar = tid >> 3, akq = (tid & 7) * 4;   // attn staging (tid<128)
    const int vk = tid >> 5;                        // values staging rows vk+8p

    const float* pAt = attn + (size_t)(b * TQ_ + q0 + ar) * TK_ + akq;
    const float* pV0 = values + (size_t)(b * TK_ + vk     ) * NV_ + v0 + v4;
    const float* pV1 = values + (size_t)(b * TK_ + vk +  8) * NV_ + v0 + v4;
    const float* pV2 = values + (size_t)(b * TK_ + vk + 16) * NV_ + v0 + v4;
    const float* pV3 = values + (size_t)(b * TK_ + vk + 24) * NV_ + v0 + v4;

    float4 af = {0.f,0.f,0.f,0.f};
    if (tid < 128) af = *(const float4*)pAt;
    float4 vf0 = *(const float4*)pV0;
    float4 vf1 = *(const float4*)pV1;
    float4 vf2 = *(const float4*)pV2;
    float4 vf3 = *(const float4*)pV3;

    float acc[2][4] = {{0.f,0.f,0.f,0.f},{0.f,0.f,0.f,0.f}};

    for (int c = 0; c < 16; ++c) {
        __syncthreads();
        if (tid < 128) {
            at[akq+0][ar] = af.x; at[akq+1][ar] = af.y;
            at[akq+2][ar] = af.z; at[akq+3][ar] = af.w;
        }
        *(float4*)&vt[vk     ][v4] = vf0;
        *(float4*)&vt[vk +  8][v4] = vf1;
        *(float4*)&vt[vk + 16][v4] = vf2;
        *(float4*)&vt[vk + 24][v4] = vf3;
        __syncthreads();
        if (c + 1 < 16) {
            pAt += 32; pV0 += 32 * NV_; pV1 += 32 * NV_;
            pV2 += 32 * NV_; pV3 += 32 * NV_;
            if (tid < 128) af = *(const float4*)pAt;
            vf0 = *(const float4*)pV0; vf1 = *(const float4*)pV1;
            vf2 = *(const float4*)pV2; vf3 = *(const float4*)pV3;
        }
#pragma unroll 8
        for (int kk = 0; kk < 32; ++kk) {
            float2 a = *(const float2*)&at[kk][r2];
            float4 v = *(const float4*)&vt[kk][v4];
            acc[0][0] = fmaf(a.x, v.x, acc[0][0]);
            acc[0][1] = fmaf(a.x, v.y, acc[0][1]);
            acc[0][2] = fmaf(a.x, v.z, acc[0][2]);
            acc[0][3] = fmaf(a.x, v.w, acc[0][3]);
            acc[1][0] = fmaf(a.y, v.x, acc[1][0]);
            acc[1][1] = fmaf(a.y, v.y, acc[1][1]);
            acc[1][2] = fmaf(a.y, v.z, acc[1][2]);
            acc[1][3] = fmaf(a.y, v.w, acc[1][3]);
        }
    }
    float4 o0 = {acc[0][0], acc[0][1], acc[0][2], acc[0][3]};
    float4 o1 = {acc[1][0], acc[1][1], acc[1][2], acc[1][3]};
    *(float4*)&outc[(size_t)(b * TQ_ + q0 + r2 + 0) * NV_ + v0 + v4] = o0;
    *(float4*)&outc[(size_t)(b * TQ_ + q0 + r2 + 1) * NV_ + v0 + v4] = o1;
}

// -------------------------------------------------------------- launch ----
extern "C" void kernel_launch(void* const* d_in, const int* in_sizes, int n_in,
                              void* d_out, int out_size, void* d_ws, size_t ws_size,
                              hipStream_t stream) {
    const float* query  = (const float*)d_in[0];
    const float* keys   = (const float*)d_in[1];
    const float* values = (const float*)d_in[2];
    const float* Wq     = (const float*)d_in[3];
    const float* bq     = (const float*)d_in[4];
    const float* Wk     = (const float*)d_in[5];
    const float* bk     = (const float*)d_in[6];
    const float* Wo     = (const float*)d_in[7];
    const float* bo     = (const float*)d_in[8];

    float* out_ctx  = (float*)d_out;                 // B*TQ*NV
    float* out_attn = out_ctx + B_ * TQ_ * NV_;      // B*TQ*TK
    float* proj_out = (float*)d_ws;                  // NROWS*H (qp then kp)
    float* qp = proj_out;
    float* kp = proj_out + NQR * H_;
    float* psum = proj_out + NROWS * H_;             // nsplit*NROWS*H

    const size_t base_f = (size_t)NROWS * H_;
    const size_t need4  = base_f * (1 + 4) * sizeof(float);
    const int nsplit = (ws_size >= need4) ? 4 : 1;
    const int kper   = NIN_ / nsplit;
    float* proj_dst  = (nsplit == 1) ? proj_out : psum;

    proj_kernel<<<dim3(NROWS / 32, nsplit), 256, 0, stream>>>(
        query, keys, Wq, Wk, bq, bk, proj_dst, nsplit, kper);
    if (nsplit > 1)
        reduce_kernel<<<(NROWS * H_ / 4) / 256, 256, 0, stream>>>(
            psum, bq, bk, proj_out, nsplit);
    scores_kernel<<<dim3(TQ_ / 4, B_), 256, 0, stream>>>(qp, kp, Wo, bo, out_attn);
    context_kernel<<<dim3(32, B_), 256, 0, stream>>>(out_attn, values, out_ctx);
}

// Round 4
// 68.613 us; speedup vs baseline: 2.9906x; 1.0351x over previous
//
#include <hip/hip_runtime.h>

// Bahdanau additive attention, f32. B=8, TQ=128, TK=512, NIN=512, H=128, NV=512.
// out = [context (B*TQ*NV), attn (B*TQ*TK)] f32.

#define B_    8
#define TQ_   128
#define TK_   512
#define NIN_  512
#define H_    128
#define NV_   512
#define NQR   (B_*TQ_)           // 1024 query rows
#define NROWS (NQR + B_*TK_)     // 5120 total projected rows

#define C2_   2.8853900817779268f   // 2*log2(e)
#define L2E_  1.4426950408889634f

__device__ __forceinline__ float fexp2(float x){ return __builtin_amdgcn_exp2f(x); }
__device__ __forceinline__ float frcp (float x){ return __builtin_amdgcn_rcpf(x); }

// ---------------------------------------------------------------- proj ----
// psum[s][row][h] = A[row, ks:ke) . W[h, ks:ke)
// grid (NROWS/16, 4): tile 16 rows x 128 h, K-chunk 32, kper=128.
// 1280 blocks = 5/CU. Microtile 2x4. Register-prefetch pipeline.
__global__ __launch_bounds__(256, 5) void proj_kernel(
        const float* __restrict__ query, const float* __restrict__ keys,
        const float* __restrict__ Wq, const float* __restrict__ Wk,
        float* __restrict__ psum, int kper) {
    __shared__ float at[32][18];     // [kk][row], 16 rows
    __shared__ float wt[32][132];    // [kk][h]
    const int tid = threadIdx.x;
    const int r0  = blockIdx.x * 16;
    const float* in; const float* W;
    if (r0 < NQR) { in = query + (size_t)r0 * NIN_;         W = Wq; }
    else          { in = keys  + (size_t)(r0 - NQR) * NIN_; W = Wk; }

    const int r2 = (tid >> 5) * 2;       // 2 rows
    const int h4 = (tid & 31) * 4;       // 4 h
    const int ar  = tid >> 4;            // A-stage row 0..15
    const int ak2 = (tid & 15) * 2;      // A-stage k pair
    const int wr  = tid >> 3;            // W-stage h row 0..31 (+32p)
    const int wkq = (tid & 7) * 4;       // W-stage k quad
    const int kb0 = blockIdx.y * kper;
    const int nc  = kper >> 5;

    const float* pA  = in + ar * NIN_ + kb0 + ak2;
    const float* pW0 = W + (wr     ) * NIN_ + kb0 + wkq;
    const float* pW1 = W + (wr + 32) * NIN_ + kb0 + wkq;
    const float* pW2 = W + (wr + 64) * NIN_ + kb0 + wkq;
    const float* pW3 = W + (wr + 96) * NIN_ + kb0 + wkq;

    float2 af  = *(const float2*)pA;
    float4 wf0 = *(const float4*)pW0;
    float4 wf1 = *(const float4*)pW1;
    float4 wf2 = *(const float4*)pW2;
    float4 wf3 = *(const float4*)pW3;

    float acc[2][4] = {{0.f,0.f,0.f,0.f},{0.f,0.f,0.f,0.f}};

    for (int c = 0; c < nc; ++c) {
        __syncthreads();
        at[ak2+0][ar] = af.x;  at[ak2+1][ar] = af.y;
        wt[wkq+0][wr   ] = wf0.x; wt[wkq+1][wr   ] = wf0.y;
        wt[wkq+2][wr   ] = wf0.z; wt[wkq+3][wr   ] = wf0.w;
        wt[wkq+0][wr+32] = wf1.x; wt[wkq+1][wr+32] = wf1.y;
        wt[wkq+2][wr+32] = wf1.z; wt[wkq+3][wr+32] = wf1.w;
        wt[wkq+0][wr+64] = wf2.x; wt[wkq+1][wr+64] = wf2.y;
        wt[wkq+2][wr+64] = wf2.z; wt[wkq+3][wr+64] = wf2.w;
        wt[wkq+0][wr+96] = wf3.x; wt[wkq+1][wr+96] = wf3.y;
        wt[wkq+2][wr+96] = wf3.z; wt[wkq+3][wr+96] = wf3.w;
        __syncthreads();
        if (c + 1 < nc) {
            pA += 32; pW0 += 32; pW1 += 32; pW2 += 32; pW3 += 32;
            af  = *(const float2*)pA;
            wf0 = *(const float4*)pW0; wf1 = *(const float4*)pW1;
            wf2 = *(const float4*)pW2; wf3 = *(const float4*)pW3;
        }
#pragma unroll 8
        for (int kk = 0; kk < 32; ++kk) {
            float2 a = *(const float2*)&at[kk][r2];
            float4 w = *(const float4*)&wt[kk][h4];
            acc[0][0] = fmaf(a.x, w.x, acc[0][0]);
            acc[0][1] = fmaf(a.x, w.y, acc[0][1]);
            acc[0][2] = fmaf(a.x, w.z, acc[0][2]);
            acc[0][3] = fmaf(a.x, w.w, acc[0][3]);
            acc[1][0] = fmaf(a.y, w.x, acc[1][0]);
            acc[1][1] = fmaf(a.y, w.y, acc[1][1]);
            acc[1][2] = fmaf(a.y, w.z, acc[1][2]);
            acc[1][3] = fmaf(a.y, w.w, acc[1][3]);
        }
    }

    float* op = psum + ((size_t)blockIdx.y * NROWS + r0) * H_;
#pragma unroll
    for (int i = 0; i < 2; ++i) {
        float4 o = {acc[i][0], acc[i][1], acc[i][2], acc[i][3]};
        *(float4*)&op[(r2 + i) * H_ + h4] = o;
    }
}

// -------------------------------------------------------------- reduce ----
// proj_out[row][h] = sum_s psum[s][row][h] + bias[h]
__global__ __launch_bounds__(256, 4) void reduce_kernel(
        const float* __restrict__ psum, const float* __restrict__ bq,
        const float* __restrict__ bk, float* __restrict__ pout) {
    const int i = blockIdx.x * 256 + threadIdx.x;    // float4 index
    const int row = i >> 5;
    const int h4  = (i & 31) * 4;
    const float* bias = (row < NQR) ? bq : bk;
    float4 s = *(const float4*)&bias[h4];
#pragma unroll
    for (int sp = 0; sp < 4; ++sp) {
        float4 p = *(const float4*)&psum[((size_t)sp * NROWS) * H_ + (size_t)i * 4];
        s.x += p.x; s.y += p.y; s.z += p.z; s.w += p.w;
    }
    *(float4*)&pout[(size_t)i * 4] = s;
}

// -------------------------------------------------------------- scores ----
// Per block: batch b, 2 q rows. scores -> softmax -> attn.
// score = bo + sumWo - 2*sum_h Wo_h/(e^(2x_h)+1)
__global__ __launch_bounds__(256, 4) void scores_kernel(
        const float* __restrict__ qp, const float* __restrict__ kp,
        const float* __restrict__ Wo, const float* __restrict__ bo,
        float* __restrict__ out_attn) {
    __shared__ float qs2[2][H_];    // q_proj * C2
    __shared__ float w2[H_];        // -2 * Wo
    __shared__ float sc[2][TK_];

    const int tid = threadIdx.x;
    const int b   = blockIdx.y;
    const int q0  = blockIdx.x * 2;
    const int lane = tid & 63;

    qs2[tid >> 7][tid & 127] =
        qp[(b * TQ_ + q0 + (tid >> 7)) * H_ + (tid & 127)] * C2_;
    if (tid < H_) w2[tid] = Wo[tid] * -2.0f;
    __syncthreads();

    float sw = w2[lane] + w2[lane + 64];
#pragma unroll
    for (int m = 1; m < 64; m <<= 1) sw += __shfl_xor(sw, m);
    const float sbase = bo[0] - 0.5f * sw;

#pragma unroll
    for (int half = 0; half < 2; ++half) {
        const int k = tid + half * 256;
        const float4* kp4 = (const float4*)&kp[(b * TK_ + k) * H_];
        float acc[2] = {0.f, 0.f};
#pragma unroll 4
        for (int hb = 0; hb < 32; ++hb) {
            float4 kv = kp4[hb];
            kv.x *= C2_; kv.y *= C2_; kv.z *= C2_; kv.w *= C2_;
            float4 wv = *(const float4*)&w2[hb * 4];
#pragma unroll
            for (int qi = 0; qi < 2; ++qi) {
                float4 qv = *(const float4*)&qs2[qi][hb * 4];
                float r0 = frcp(fexp2(qv.x + kv.x) + 1.0f);
                float r1 = frcp(fexp2(qv.y + kv.y) + 1.0f);
                float r2 = frcp(fexp2(qv.z + kv.z) + 1.0f);
                float r3 = frcp(fexp2(qv.w + kv.w) + 1.0f);
                acc[qi] = fmaf(wv.x, r0, acc[qi]);
                acc[qi] = fmaf(wv.y, r1, acc[qi]);
                acc[qi] = fmaf(wv.z, r2, acc[qi]);
                acc[qi] = fmaf(wv.w, r3, acc[qi]);
            }
        }
        sc[0][k] = acc[0] + sbase;
        sc[1][k] = acc[1] + sbase;
    }
    __syncthreads();

    // softmax: waves 0,1 -> rows 0,1 (8 scores per lane); waves 2,3 idle
    const int w = tid >> 6;
    if (w < 2) {
        float4 sA = *(const float4*)&sc[w][lane * 8];
        float4 sB = *(const float4*)&sc[w][lane * 8 + 4];
        float m = fmaxf(fmaxf(fmaxf(sA.x, sA.y), fmaxf(sA.z, sA.w)),
                        fmaxf(fmaxf(sB.x, sB.y), fmaxf(sB.z, sB.w)));
#pragma unroll
        for (int mask = 1; mask < 64; mask <<= 1) m = fmaxf(m, __shfl_xor(m, mask));
        float4 eA, eB;
        eA.x = fexp2((sA.x - m) * L2E_); eA.y = fexp2((sA.y - m) * L2E_);
        eA.z = fexp2((sA.z - m) * L2E_); eA.w = fexp2((sA.w - m) * L2E_);
        eB.x = fexp2((sB.x - m) * L2E_); eB.y = fexp2((sB.y - m) * L2E_);
        eB.z = fexp2((sB.z - m) * L2E_); eB.w = fexp2((sB.w - m) * L2E_);
        float s = eA.x + eA.y + eA.z + eA.w + eB.x + eB.y + eB.z + eB.w;
#pragma unroll
        for (int mask = 1; mask < 64; mask <<= 1) s += __shfl_xor(s, mask);
        float inv = frcp(s);
        eA.x *= inv; eA.y *= inv; eA.z *= inv; eA.w *= inv;
        eB.x *= inv; eB.y *= inv; eB.z *= inv; eB.w *= inv;
        float4* op = (float4*)&out_attn[(b * TQ_ + q0 + w) * TK_ + lane * 8];
        op[0] = eA; op[1] = eB;
    }
}

// ------------------------------------------------------------- context ----
// One block: 16 q x 128 v, full K=512, reg-prefetch pipeline.
// grid (32 = 8 q-tiles x 4 v-tiles, B)
__global__ __launch_bounds__(256, 4) void context_kernel(
        const float* __restrict__ attn, const float* __restrict__ values,
        float* __restrict__ outc) {
    __shared__ float at[32][20];    // [kk][q]
    __shared__ float vt[32][132];   // [kk][v]

    const int tid = threadIdx.x;
    const int b   = blockIdx.y;
    const int q0  = (blockIdx.x >> 2) * 16;
    const int v0  = (blockIdx.x & 3) * 128;

    const int tx = tid & 31, ty = tid >> 5;
    const int v4 = tx * 4,   r2 = ty * 2;
    const int ar = tid >> 3, akq = (tid & 7) * 4;   // attn staging (tid<128)
    const int vk = tid >> 5;                        // values staging rows vk+8p

    const float* pAt = attn + (size_t)(b * TQ_ + q0 + ar) * TK_ + akq;
    const float* pV0 = values + (size_t)(b * TK_ + vk     ) * NV_ + v0 + v4;
    const float* pV1 = values + (size_t)(b * TK_ + vk +  8) * NV_ + v0 + v4;
    const float* pV2 = values + (size_t)(b * TK_ + vk + 16) * NV_ + v0 + v4;
    const float* pV3 = values + (size_t)(b * TK_ + vk + 24) * NV_ + v0 + v4;

    float4 af = {0.f,0.f,0.f,0.f};
    if (tid < 128) af = *(const float4*)pAt;
    float4 vf0 = *(const float4*)pV0;
    float4 vf1 = *(const float4*)pV1;
    float4 vf2 = *(const float4*)pV2;
    float4 vf3 = *(const float4*)pV3;

    float acc[2][4] = {{0.f,0.f,0.f,0.f},{0.f,0.f,0.f,0.f}};

    for (int c = 0; c < 16; ++c) {
        __syncthreads();
        if (tid < 128) {
            at[akq+0][ar] = af.x; at[akq+1][ar] = af.y;
            at[akq+2][ar] = af.z; at[akq+3][ar] = af.w;
        }
        *(float4*)&vt[vk     ][v4] = vf0;
        *(float4*)&vt[vk +  8][v4] = vf1;
        *(float4*)&vt[vk + 16][v4] = vf2;
        *(float4*)&vt[vk + 24][v4] = vf3;
        __syncthreads();
        if (c + 1 < 16) {
            pAt += 32; pV0 += 32 * NV_; pV1 += 32 * NV_;
            pV2 += 32 * NV_; pV3 += 32 * NV_;
            if (tid < 128) af = *(const float4*)pAt;
            vf0 = *(const float4*)pV0; vf1 = *(const float4*)pV1;
            vf2 = *(const float4*)pV2; vf3 = *(const float4*)pV3;
        }
#pragma unroll 8
        for (int kk = 0; kk < 32; ++kk) {
            float2 a = *(const float2*)&at[kk][r2];
            float4 v = *(const float4*)&vt[kk][v4];
            acc[0][0] = fmaf(a.x, v.x, acc[0][0]);
            acc[0][1] = fmaf(a.x, v.y, acc[0][1]);
            acc[0][2] = fmaf(a.x, v.z, acc[0][2]);
            acc[0][3] = fmaf(a.x, v.w, acc[0][3]);
            acc[1][0] = fmaf(a.y, v.x, acc[1][0]);
            acc[1][1] = fmaf(a.y, v.y, acc[1][1]);
            acc[1][2] = fmaf(a.y, v.z, acc[1][2]);
            acc[1][3] = fmaf(a.y, v.w, acc[1][3]);
        }
    }
    float4 o0 = {acc[0][0], acc[0][1], acc[0][2], acc[0][3]};
    float4 o1 = {acc[1][0], acc[1][1], acc[1][2], acc[1][3]};
    *(float4*)&outc[(size_t)(b * TQ_ + q0 + r2 + 0) * NV_ + v0 + v4] = o0;
    *(float4*)&outc[(size_t)(b * TQ_ + q0 + r2 + 1) * NV_ + v0 + v4] = o1;
}

// -------------------------------------------------------------- launch ----
extern "C" void kernel_launch(void* const* d_in, const int* in_sizes, int n_in,
                              void* d_out, int out_size, void* d_ws, size_t ws_size,
                              hipStream_t stream) {
    const float* query  = (const float*)d_in[0];
    const float* keys   = (const float*)d_in[1];
    const float* values = (const float*)d_in[2];
    const float* Wq     = (const float*)d_in[3];
    const float* bq     = (const float*)d_in[4];
    const float* Wk     = (const float*)d_in[5];
    const float* bk     = (const float*)d_in[6];
    const float* Wo     = (const float*)d_in[7];
    const float* bo     = (const float*)d_in[8];

    float* out_ctx  = (float*)d_out;                 // B*TQ*NV
    float* out_attn = out_ctx + B_ * TQ_ * NV_;      // B*TQ*TK
    float* proj_out = (float*)d_ws;                  // NROWS*H (qp then kp)
    float* qp = proj_out;
    float* kp = proj_out + NQR * H_;
    float* psum = proj_out + NROWS * H_;             // 4*NROWS*H

    proj_kernel<<<dim3(NROWS / 16, 4), 256, 0, stream>>>(
        query, keys, Wq, Wk, psum, NIN_ / 4);
    reduce_kernel<<<(NROWS * H_ / 4) / 256, 256, 0, stream>>>(
        psum, bq, bk, proj_out);
    scores_kernel<<<dim3(TQ_ / 2, B_), 256, 0, stream>>>(qp, kp, Wo, bo, out_attn);
    context_kernel<<<dim3(32, B_), 256, 0, stream>>>(out_attn, values, out_ctx);
}